// Round 2
// baseline (69.057 us; speedup 1.0000x reference)
//
#include <hip/hip_runtime.h>
#include <hip/hip_bf16.h>

#define NSLICE 6
#define NPIX   4096
// sqrt((1/sigma^2) * log2(e)), sigma = 0.1  ->  sqrt(144.26950408889634)
#define SQRT_C 12.011224459360945f

__device__ __forceinline__ float fast_exp2(float x) {
#if defined(__has_builtin)
#if __has_builtin(__builtin_amdgcn_exp2f)
    return __builtin_amdgcn_exp2f(x);          // v_exp_f32 directly
#else
    return __expf(x * 0.6931471805599453f);    // exp(x*ln2) = 2^x
#endif
#else
    return __expf(x * 0.6931471805599453f);
#endif
}

// Block: 256 threads = 32 output pixels x 8 q-chunks (q4-index = 8*i + c).
// Grid: 6 slices * 128 pixel-tiles = 768 blocks (~3 blocks/CU).
__global__ __launch_bounds__(256) void bilateral_kernel(
        const float* __restrict__ x,
        float* __restrict__ out) {
    __shared__ float xs[NPIX];   // sqrt(C) * x_q, 16 KB

    const int tid   = threadIdx.x;
    const int s     = blockIdx.x >> 7;     // slice: 128 blocks per slice
    const int ptile = blockIdx.x & 127;    // 32 pixels per tile
    const float* xg = x + s * NPIX;

    // Stage pre-scaled pixels into LDS: float4 global loads, float4 LDS writes.
    const float4* xg4 = (const float4*)xg;
    float4* xs4w = (float4*)xs;
    #pragma unroll
    for (int j = 0; j < NPIX / 4 / 256; ++j) {   // 4 iterations
        int i4 = j * 256 + tid;
        float4 v = xg4[i4];
        xs4w[i4] = make_float4(v.x * SQRT_C, v.y * SQRT_C,
                               v.z * SQRT_C, v.w * SQRT_C);
    }
    __syncthreads();

    const int c = tid & 7;                 // q-chunk within the 8-lane group
    const int p = ptile * 32 + (tid >> 3);
    const float xp = xs[p];                // broadcast (8 lanes share p)

    float num = 0.f, den = 0.f;            // num accumulates k * (sqrtC * xq)
    const float4* xs4 = (const float4*)xs;
    #pragma unroll 4
    for (int i = 0; i < NPIX / 4 / 8; ++i) {     // 128 iters x 4 q each
        float4 v = xs4[i * 8 + c];         // ds_read_b128, bank-disjoint per c
        float d0 = v.x - xp;
        float d1 = v.y - xp;
        float d2 = v.z - xp;
        float d3 = v.w - xp;
        float k0 = fast_exp2(-(d0 * d0));  // exp2(-C*(xq-xp)^2), neg modifier free
        float k1 = fast_exp2(-(d1 * d1));
        float k2 = fast_exp2(-(d2 * d2));
        float k3 = fast_exp2(-(d3 * d3));
        num = fmaf(k0, v.x, num);  den += k0;
        num = fmaf(k1, v.y, num);  den += k1;
        num = fmaf(k2, v.z, num);  den += k2;
        num = fmaf(k3, v.w, num);  den += k3;
    }

    // Reduce the 8 q-chunks within each consecutive-8-lane group.
    #pragma unroll
    for (int m = 1; m < 8; m <<= 1) {
        num += __shfl_xor(num, m);
        den += __shfl_xor(den, m);
    }

    if (c == 0) {
        // num = sqrtC * sum(k*xq); den = sum(k)  ->  out = num/(den*sqrtC)
        out[s * NPIX + p] = num / (den * SQRT_C);
    }
}

extern "C" void kernel_launch(void* const* d_in, const int* in_sizes, int n_in,
                              void* d_out, int out_size, void* d_ws, size_t ws_size,
                              hipStream_t stream) {
    const float* x = (const float*)d_in[0];
    float* out = (float*)d_out;
    bilateral_kernel<<<dim3(NSLICE * 128), dim3(256), 0, stream>>>(x, out);
}